// Round 1
// baseline (11661.601 us; speedup 1.0000x reference)
//
#include <hip/hip_runtime.h>
#include <cstdint>
#include <cstddef>

#define THREADS 256
#define ET 64

__device__ __forceinline__ float reluf(float v) { return fmaxf(v, 0.0f); }

// ---------------------------------------------------------------------------
// Edge pipeline: e = relu(raw@ew1+eb1)@ew2+eb2 ; gated = e*(clip(pol,0,1)+.01)
// emb = gated@lew+leb ; msg = relu(x[src]+emb) ; atomic scatter into aggr[dst]
// Block: 64 edges, 256 threads. tid = e_local(0..63) + 64*c (c = dim group).
// ---------------------------------------------------------------------------
__global__ __launch_bounds__(THREADS) void edge_kernel(
    const float* __restrict__ x, const int* __restrict__ ei,
    const float* __restrict__ ea,
    const float* __restrict__ ew1, const float* __restrict__ eb1,
    const float* __restrict__ ew2, const float* __restrict__ eb2,
    const float* __restrict__ lew, const float* __restrict__ leb,
    float* __restrict__ aggr, int E)
{
    __shared__ float s_attr[ET * 17];
    __shared__ float s_hid[128 * ET];   // [j][e], reused for gated
    __shared__ int   s_src[ET];
    __shared__ int   s_dst[ET];

    const int tid = threadIdx.x;
    const long long eb = (long long)blockIdx.x * ET;

    for (int i = tid; i < ET * 17; i += THREADS) s_attr[i] = ea[eb * 17 + i];
    if (tid < ET) {
        s_src[tid] = ei[eb + tid];
        s_dst[tid] = ei[(long long)E + eb + tid];
    }
    __syncthreads();

    const int el = tid & 63;
    const int c  = tid >> 6;

    // ---- phase 1: hid = relu(raw @ ew1 + eb1), this thread does 32 dims ----
    float acc[32];
#pragma unroll
    for (int j4 = 0; j4 < 8; ++j4) {
        float4 b = *(const float4*)(eb1 + c * 32 + j4 * 4);
        acc[j4*4+0] = b.x; acc[j4*4+1] = b.y; acc[j4*4+2] = b.z; acc[j4*4+3] = b.w;
    }
#pragma unroll
    for (int k = 0; k < 16; ++k) {
        float rk = s_attr[el * 17 + 1 + k];
#pragma unroll
        for (int j4 = 0; j4 < 8; ++j4) {
            float4 w = *(const float4*)(ew1 + k * 128 + c * 32 + j4 * 4);
            acc[j4*4+0] = fmaf(rk, w.x, acc[j4*4+0]);
            acc[j4*4+1] = fmaf(rk, w.y, acc[j4*4+1]);
            acc[j4*4+2] = fmaf(rk, w.z, acc[j4*4+2]);
            acc[j4*4+3] = fmaf(rk, w.w, acc[j4*4+3]);
        }
    }
#pragma unroll
    for (int j = 0; j < 32; ++j) s_hid[(c * 32 + j) * ET + el] = reluf(acc[j]);
    __syncthreads();

    // ---- phase 2: e = hid @ ew2 + eb2 ----
#pragma unroll
    for (int j4 = 0; j4 < 8; ++j4) {
        float4 b = *(const float4*)(eb2 + c * 32 + j4 * 4);
        acc[j4*4+0] = b.x; acc[j4*4+1] = b.y; acc[j4*4+2] = b.z; acc[j4*4+3] = b.w;
    }
    for (int k = 0; k < 128; ++k) {
        float hk = s_hid[k * ET + el];
#pragma unroll
        for (int j4 = 0; j4 < 8; ++j4) {
            float4 w = *(const float4*)(ew2 + k * 128 + c * 32 + j4 * 4);
            acc[j4*4+0] = fmaf(hk, w.x, acc[j4*4+0]);
            acc[j4*4+1] = fmaf(hk, w.y, acc[j4*4+1]);
            acc[j4*4+2] = fmaf(hk, w.z, acc[j4*4+2]);
            acc[j4*4+3] = fmaf(hk, w.w, acc[j4*4+3]);
        }
    }
    float pol = fminf(fmaxf(s_attr[el * 17], 0.0f), 1.0f) + 0.01f;
    __syncthreads();  // all s_hid reads done before overwrite
#pragma unroll
    for (int j = 0; j < 32; ++j) s_hid[(c * 32 + j) * ET + el] = acc[j] * pol;
    __syncthreads();

    // ---- phase 3: emb = gated @ lew + leb, this thread does 64 dims ----
    float acc3[64];
#pragma unroll
    for (int d4 = 0; d4 < 16; ++d4) {
        float4 b = *(const float4*)(leb + c * 64 + d4 * 4);
        acc3[d4*4+0] = b.x; acc3[d4*4+1] = b.y; acc3[d4*4+2] = b.z; acc3[d4*4+3] = b.w;
    }
    for (int k = 0; k < 128; ++k) {
        float g = s_hid[k * ET + el];
#pragma unroll
        for (int d4 = 0; d4 < 16; ++d4) {
            float4 w = *(const float4*)(lew + k * 256 + c * 64 + d4 * 4);
            acc3[d4*4+0] = fmaf(g, w.x, acc3[d4*4+0]);
            acc3[d4*4+1] = fmaf(g, w.y, acc3[d4*4+1]);
            acc3[d4*4+2] = fmaf(g, w.z, acc3[d4*4+2]);
            acc3[d4*4+3] = fmaf(g, w.w, acc3[d4*4+3]);
        }
    }

    const int src = s_src[el];
    const int dst = s_dst[el];
    const float4* xr = (const float4*)(x + (size_t)src * 256 + c * 64);
    float* ar = aggr + (size_t)dst * 256 + c * 64;
#pragma unroll
    for (int q = 0; q < 16; ++q) {
        float4 xv = xr[q];
        float m0 = reluf(acc3[q*4+0] + xv.x);
        float m1 = reluf(acc3[q*4+1] + xv.y);
        float m2 = reluf(acc3[q*4+2] + xv.z);
        float m3 = reluf(acc3[q*4+3] + xv.w);
        unsafeAtomicAdd(ar + q * 4 + 0, m0);
        unsafeAtomicAdd(ar + q * 4 + 1, m1);
        unsafeAtomicAdd(ar + q * 4 + 2, m2);
        unsafeAtomicAdd(ar + q * 4 + 3, m3);
    }
}

// ---------------------------------------------------------------------------
// C[N,256] = (A1 (+A2)) @ W[256,256] + bias.  64-row tile, BK=32, 8x8 regs.
// ---------------------------------------------------------------------------
__global__ __launch_bounds__(THREADS) void gemm_kernel(
    const float* __restrict__ A1, const float* __restrict__ A2,
    const float* __restrict__ W, const float* __restrict__ bias,
    float* __restrict__ C, int N)
{
    __shared__ float s_a[32 * 64];    // [k][n]
    __shared__ float s_w[32 * 256];   // [k][d]

    const int tid = threadIdx.x;
    const int nb = blockIdx.x * 64;
    const int ni = tid >> 5;   // 0..7
    const int di = tid & 31;   // 0..31

    float acc[8][8];
#pragma unroll
    for (int r = 0; r < 8; ++r)
#pragma unroll
        for (int cc = 0; cc < 8; ++cc) acc[r][cc] = 0.0f;

    const int ln = tid >> 2;   // 0..63 (load row)
    const int kc = tid & 3;    // k-chunk
    const int arow = (nb + ln < N) ? (nb + ln) : (N - 1);
    const float* a1p = A1 + (size_t)arow * 256 + kc * 8;
    const float* a2p = A2 ? (A2 + (size_t)arow * 256 + kc * 8) : nullptr;

    for (int kb = 0; kb < 256; kb += 32) {
        float4 v0 = *(const float4*)(a1p + kb);
        float4 v1 = *(const float4*)(a1p + kb + 4);
        if (A2) {
            float4 u0 = *(const float4*)(a2p + kb);
            float4 u1 = *(const float4*)(a2p + kb + 4);
            v0.x += u0.x; v0.y += u0.y; v0.z += u0.z; v0.w += u0.w;
            v1.x += u1.x; v1.y += u1.y; v1.z += u1.z; v1.w += u1.w;
        }
        __syncthreads();  // previous tile's compute done
        s_a[(kc*8+0)*64 + ln] = v0.x; s_a[(kc*8+1)*64 + ln] = v0.y;
        s_a[(kc*8+2)*64 + ln] = v0.z; s_a[(kc*8+3)*64 + ln] = v0.w;
        s_a[(kc*8+4)*64 + ln] = v1.x; s_a[(kc*8+5)*64 + ln] = v1.y;
        s_a[(kc*8+6)*64 + ln] = v1.z; s_a[(kc*8+7)*64 + ln] = v1.w;
#pragma unroll
        for (int i = 0; i < 8; ++i) {
            int idx = tid + i * 256;          // float4 index 0..2047
            int row = idx >> 6, c4 = idx & 63;
            *(float4*)&s_w[row * 256 + c4 * 4] =
                *(const float4*)(W + (size_t)(kb + row) * 256 + c4 * 4);
        }
        __syncthreads();
#pragma unroll
        for (int kk = 0; kk < 32; ++kk) {
            float4 a0 = *(const float4*)&s_a[kk * 64 + ni * 4];
            float4 a1 = *(const float4*)&s_a[kk * 64 + ni * 4 + 32];
            float4 w0 = *(const float4*)&s_w[kk * 256 + di * 4];
            float4 w1 = *(const float4*)&s_w[kk * 256 + di * 4 + 128];
            float ar8[8] = {a0.x, a0.y, a0.z, a0.w, a1.x, a1.y, a1.z, a1.w};
            float wc8[8] = {w0.x, w0.y, w0.z, w0.w, w1.x, w1.y, w1.z, w1.w};
#pragma unroll
            for (int r = 0; r < 8; ++r)
#pragma unroll
                for (int cc = 0; cc < 8; ++cc)
                    acc[r][cc] = fmaf(ar8[r], wc8[cc], acc[r][cc]);
        }
    }

    float4 bb0 = *(const float4*)(bias + di * 4);
    float4 bb1 = *(const float4*)(bias + di * 4 + 128);
#pragma unroll
    for (int r = 0; r < 8; ++r) {
        int node = nb + ((r < 4) ? (ni * 4 + r) : (32 + ni * 4 + (r - 4)));
        if (node < N) {
            float4 o0 = {acc[r][0] + bb0.x, acc[r][1] + bb0.y,
                         acc[r][2] + bb0.z, acc[r][3] + bb0.w};
            float4 o1 = {acc[r][4] + bb1.x, acc[r][5] + bb1.y,
                         acc[r][6] + bb1.z, acc[r][7] + bb1.w};
            *(float4*)(C + (size_t)node * 256 + di * 4) = o0;
            *(float4*)(C + (size_t)node * 256 + di * 4 + 128) = o1;
        }
    }
}

// ---------------------------------------------------------------------------
// y = relu(LN(h1)*g + b) ; wave per node
// ---------------------------------------------------------------------------
__global__ __launch_bounds__(THREADS) void ln_relu_kernel(
    const float* __restrict__ h1, const float* __restrict__ g,
    const float* __restrict__ b, float* __restrict__ y, int N)
{
    const int wave = threadIdx.x >> 6;
    const int lane = threadIdx.x & 63;
    const int node = blockIdx.x * 4 + wave;
    if (node >= N) return;

    float4 v = *(const float4*)(h1 + (size_t)node * 256 + lane * 4);
    float s = v.x + v.y + v.z + v.w;
#pragma unroll
    for (int o = 32; o > 0; o >>= 1) s += __shfl_xor(s, o);
    float mu = s * (1.0f / 256.0f);
    float4 d = {v.x - mu, v.y - mu, v.z - mu, v.w - mu};
    float q = d.x * d.x + d.y * d.y + d.z * d.z + d.w * d.w;
#pragma unroll
    for (int o = 32; o > 0; o >>= 1) q += __shfl_xor(q, o);
    float var = q * (1.0f / 256.0f);
    float sc = 1.0f / sqrtf(var + 1e-5f);

    float4 gg = *(const float4*)(g + lane * 4);
    float4 bb = *(const float4*)(b + lane * 4);
    float4 o;
    o.x = reluf(d.x * sc * gg.x + bb.x);
    o.y = reluf(d.y * sc * gg.y + bb.y);
    o.z = reluf(d.z * sc * gg.z + bb.z);
    o.w = reluf(d.w * sc * gg.w + bb.w);
    *(float4*)(y + (size_t)node * 256 + lane * 4) = o;
}

extern "C" void kernel_launch(void* const* d_in, const int* in_sizes, int n_in,
                              void* d_out, int out_size, void* d_ws, size_t ws_size,
                              hipStream_t stream) {
    const float* x   = (const float*)d_in[0];
    const int*   ei  = (const int*)d_in[1];
    const float* ea  = (const float*)d_in[2];
    const float* ew1 = (const float*)d_in[3];
    const float* eb1 = (const float*)d_in[4];
    const float* ew2 = (const float*)d_in[5];
    const float* eb2 = (const float*)d_in[6];
    const float* lew = (const float*)d_in[7];
    const float* leb = (const float*)d_in[8];
    const float* w1  = (const float*)d_in[9];
    const float* b1  = (const float*)d_in[10];
    const float* lng = (const float*)d_in[11];
    const float* lnb = (const float*)d_in[12];
    const float* w2  = (const float*)d_in[13];
    const float* b2  = (const float*)d_in[14];
    float* out = (float*)d_out;

    const int N = in_sizes[0] / 256;
    const int E = in_sizes[1] / 2;

    float* aggr = (float*)d_ws;                    // N*256 f32
    float* h1   = aggr + (size_t)N * 256;          // N*256 f32

    hipMemsetAsync(aggr, 0, (size_t)N * 256 * sizeof(float), stream);

    edge_kernel<<<E / ET, THREADS, 0, stream>>>(x, ei, ea, ew1, eb1, ew2, eb2,
                                                lew, leb, aggr, E);

    const int gb = (N + 63) / 64;
    gemm_kernel<<<gb, THREADS, 0, stream>>>(x, aggr, w1, b1, h1, N);
    ln_relu_kernel<<<(N + 3) / 4, THREADS, 0, stream>>>(h1, lng, lnb, aggr, N);
    gemm_kernel<<<gb, THREADS, 0, stream>>>(aggr, nullptr, w2, b2, out, N);
}

// Round 2
// 5102.231 us; speedup vs baseline: 2.2856x; 2.2856x over previous
//
#include <hip/hip_runtime.h>
#include <cstdint>
#include <cstddef>

#define THREADS 256
#define ET 64

__device__ __forceinline__ float reluf(float v) { return fmaxf(v, 0.0f); }

// ---------------------------------------------------------------------------
// Counting sort of edges by dst: hist -> exclusive scan -> scatter(perm)
// ---------------------------------------------------------------------------
__global__ __launch_bounds__(256) void hist_kernel(
    const int* __restrict__ ei, int* __restrict__ counts, int E)
{
    int e = blockIdx.x * 256 + threadIdx.x;
    if (e < E) atomicAdd(&counts[ei[(long long)E + e]], 1);
}

__global__ __launch_bounds__(1024) void scan_kernel(int* __restrict__ counts, int N)
{
    __shared__ int wsum[16];
    __shared__ int carry;
    const int tid = threadIdx.x;
    const int lane = tid & 63, wid = tid >> 6;
    if (tid == 0) carry = 0;
    __syncthreads();
    for (int chunk = 0; chunk < N; chunk += 1024) {
        int idx = chunk + tid;
        int v = (idx < N) ? counts[idx] : 0;
        int incl = v;
#pragma unroll
        for (int off = 1; off < 64; off <<= 1) {
            int t = __shfl_up(incl, off);
            if (lane >= off) incl += t;
        }
        if (lane == 63) wsum[wid] = incl;
        __syncthreads();
        int wpre = 0, tot = 0;
#pragma unroll
        for (int w = 0; w < 16; ++w) {
            int s = wsum[w];
            tot += s;
            if (w < wid) wpre += s;
        }
        int b = carry;
        if (idx < N) counts[idx] = b + wpre + incl - v;
        __syncthreads();
        if (tid == 0) carry = b + tot;
        __syncthreads();
    }
}

__global__ __launch_bounds__(256) void scatter_kernel(
    const int* __restrict__ ei, int* __restrict__ cursor,
    int* __restrict__ perm, int E)
{
    int e = blockIdx.x * 256 + threadIdx.x;
    if (e < E) {
        int d = ei[(long long)E + e];
        int pos = atomicAdd(&cursor[d], 1);
        perm[pos] = e;
    }
}

// ---------------------------------------------------------------------------
// Edge pipeline on dst-sorted edges. Block: 64 edges, 256 threads.
// tid = el(0..63) + 64*c. After computing msg in regs, wave-level segmented
// suffix-sum over lanes (dst sorted), leaders do the (few) atomics.
// ---------------------------------------------------------------------------
__global__ __launch_bounds__(THREADS) void edge_kernel(
    const float* __restrict__ x, const int* __restrict__ ei,
    const float* __restrict__ ea,
    const float* __restrict__ ew1, const float* __restrict__ eb1,
    const float* __restrict__ ew2, const float* __restrict__ eb2,
    const float* __restrict__ lew, const float* __restrict__ leb,
    const int* __restrict__ perm,
    float* __restrict__ aggr, int E)
{
    __shared__ float s_attr[ET * 17];
    __shared__ float s_hid[128 * ET];   // [j][e], reused for gated
    __shared__ int   s_pe[ET];
    __shared__ int   s_src[ET];
    __shared__ int   s_dst[ET];

    const int tid = threadIdx.x;
    const long long eb = (long long)blockIdx.x * ET;

    if (tid < ET) {
        int e = perm[eb + tid];
        s_pe[tid]  = e;
        s_src[tid] = ei[e];
        s_dst[tid] = ei[(long long)E + e];
    }
    __syncthreads();
    for (int i = tid; i < ET * 17; i += THREADS) {
        int idx = i / 17;
        int k = i - idx * 17;
        s_attr[i] = ea[(size_t)s_pe[idx] * 17 + k];
    }
    __syncthreads();

    const int el = tid & 63;
    const int c  = tid >> 6;

    // ---- phase 1: hid = relu(raw @ ew1 + eb1), this thread does 32 dims ----
    float acc[32];
#pragma unroll
    for (int j4 = 0; j4 < 8; ++j4) {
        float4 b = *(const float4*)(eb1 + c * 32 + j4 * 4);
        acc[j4*4+0] = b.x; acc[j4*4+1] = b.y; acc[j4*4+2] = b.z; acc[j4*4+3] = b.w;
    }
#pragma unroll
    for (int k = 0; k < 16; ++k) {
        float rk = s_attr[el * 17 + 1 + k];
#pragma unroll
        for (int j4 = 0; j4 < 8; ++j4) {
            float4 w = *(const float4*)(ew1 + k * 128 + c * 32 + j4 * 4);
            acc[j4*4+0] = fmaf(rk, w.x, acc[j4*4+0]);
            acc[j4*4+1] = fmaf(rk, w.y, acc[j4*4+1]);
            acc[j4*4+2] = fmaf(rk, w.z, acc[j4*4+2]);
            acc[j4*4+3] = fmaf(rk, w.w, acc[j4*4+3]);
        }
    }
#pragma unroll
    for (int j = 0; j < 32; ++j) s_hid[(c * 32 + j) * ET + el] = reluf(acc[j]);
    __syncthreads();

    // ---- phase 2: e = hid @ ew2 + eb2 ----
#pragma unroll
    for (int j4 = 0; j4 < 8; ++j4) {
        float4 b = *(const float4*)(eb2 + c * 32 + j4 * 4);
        acc[j4*4+0] = b.x; acc[j4*4+1] = b.y; acc[j4*4+2] = b.z; acc[j4*4+3] = b.w;
    }
    for (int k = 0; k < 128; ++k) {
        float hk = s_hid[k * ET + el];
#pragma unroll
        for (int j4 = 0; j4 < 8; ++j4) {
            float4 w = *(const float4*)(ew2 + k * 128 + c * 32 + j4 * 4);
            acc[j4*4+0] = fmaf(hk, w.x, acc[j4*4+0]);
            acc[j4*4+1] = fmaf(hk, w.y, acc[j4*4+1]);
            acc[j4*4+2] = fmaf(hk, w.z, acc[j4*4+2]);
            acc[j4*4+3] = fmaf(hk, w.w, acc[j4*4+3]);
        }
    }
    float pol = fminf(fmaxf(s_attr[el * 17], 0.0f), 1.0f) + 0.01f;
    __syncthreads();  // all s_hid reads done before overwrite
#pragma unroll
    for (int j = 0; j < 32; ++j) s_hid[(c * 32 + j) * ET + el] = acc[j] * pol;
    __syncthreads();

    // ---- phase 3: emb = gated @ lew + leb, this thread does 64 dims ----
    float acc3[64];
#pragma unroll
    for (int d4 = 0; d4 < 16; ++d4) {
        float4 b = *(const float4*)(leb + c * 64 + d4 * 4);
        acc3[d4*4+0] = b.x; acc3[d4*4+1] = b.y; acc3[d4*4+2] = b.z; acc3[d4*4+3] = b.w;
    }
    for (int k = 0; k < 128; ++k) {
        float g = s_hid[k * ET + el];
#pragma unroll
        for (int d4 = 0; d4 < 16; ++d4) {
            float4 w = *(const float4*)(lew + k * 256 + c * 64 + d4 * 4);
            acc3[d4*4+0] = fmaf(g, w.x, acc3[d4*4+0]);
            acc3[d4*4+1] = fmaf(g, w.y, acc3[d4*4+1]);
            acc3[d4*4+2] = fmaf(g, w.z, acc3[d4*4+2]);
            acc3[d4*4+3] = fmaf(g, w.w, acc3[d4*4+3]);
        }
    }

    // ---- msg = relu(x[src] + emb) ----
    const int src = s_src[el];
    const int dst = s_dst[el];
    const float4* xr = (const float4*)(x + (size_t)src * 256 + c * 64);
#pragma unroll
    for (int q = 0; q < 16; ++q) {
        float4 xv = xr[q];
        acc3[q*4+0] = reluf(acc3[q*4+0] + xv.x);
        acc3[q*4+1] = reluf(acc3[q*4+1] + xv.y);
        acc3[q*4+2] = reluf(acc3[q*4+2] + xv.z);
        acc3[q*4+3] = reluf(acc3[q*4+3] + xv.w);
    }

    // ---- segmented suffix-sum across the wave (dst ascending within block) --
#pragma unroll
    for (int d = 1; d < 64; d <<= 1) {
        int od = __shfl_down(dst, d);
        bool ok = (el + d < 64) && (od == dst);
#pragma unroll
        for (int q = 0; q < 64; ++q) {
            float ov = __shfl_down(acc3[q], d);
            acc3[q] = ok ? acc3[q] + ov : acc3[q];
        }
    }
    int up = __shfl_up(dst, 1);
    bool leader = (el == 0) || (up != dst);
    if (leader) {
        float* ar = aggr + (size_t)dst * 256 + c * 64;
#pragma unroll
        for (int q = 0; q < 64; ++q) unsafeAtomicAdd(ar + q, acc3[q]);
    }
}

// ---------------------------------------------------------------------------
// C[N,256] = (A1 (+A2)) @ W[256,256] + bias.  64-row tile, BK=32, 8x8 regs.
// ---------------------------------------------------------------------------
__global__ __launch_bounds__(THREADS) void gemm_kernel(
    const float* __restrict__ A1, const float* __restrict__ A2,
    const float* __restrict__ W, const float* __restrict__ bias,
    float* __restrict__ C, int N)
{
    __shared__ float s_a[32 * 64];    // [k][n]
    __shared__ float s_w[32 * 256];   // [k][d]

    const int tid = threadIdx.x;
    const int nb = blockIdx.x * 64;
    const int ni = tid >> 5;   // 0..7
    const int di = tid & 31;   // 0..31

    float acc[8][8];
#pragma unroll
    for (int r = 0; r < 8; ++r)
#pragma unroll
        for (int cc = 0; cc < 8; ++cc) acc[r][cc] = 0.0f;

    const int ln = tid >> 2;   // 0..63 (load row)
    const int kc = tid & 3;    // k-chunk
    const int arow = (nb + ln < N) ? (nb + ln) : (N - 1);
    const float* a1p = A1 + (size_t)arow * 256 + kc * 8;
    const float* a2p = A2 ? (A2 + (size_t)arow * 256 + kc * 8) : nullptr;

    for (int kb = 0; kb < 256; kb += 32) {
        float4 v0 = *(const float4*)(a1p + kb);
        float4 v1 = *(const float4*)(a1p + kb + 4);
        if (A2) {
            float4 u0 = *(const float4*)(a2p + kb);
            float4 u1 = *(const float4*)(a2p + kb + 4);
            v0.x += u0.x; v0.y += u0.y; v0.z += u0.z; v0.w += u0.w;
            v1.x += u1.x; v1.y += u1.y; v1.z += u1.z; v1.w += u1.w;
        }
        __syncthreads();  // previous tile's compute done
        s_a[(kc*8+0)*64 + ln] = v0.x; s_a[(kc*8+1)*64 + ln] = v0.y;
        s_a[(kc*8+2)*64 + ln] = v0.z; s_a[(kc*8+3)*64 + ln] = v0.w;
        s_a[(kc*8+4)*64 + ln] = v1.x; s_a[(kc*8+5)*64 + ln] = v1.y;
        s_a[(kc*8+6)*64 + ln] = v1.z; s_a[(kc*8+7)*64 + ln] = v1.w;
#pragma unroll
        for (int i = 0; i < 8; ++i) {
            int idx = tid + i * 256;          // float4 index 0..2047
            int row = idx >> 6, c4 = idx & 63;
            *(float4*)&s_w[row * 256 + c4 * 4] =
                *(const float4*)(W + (size_t)(kb + row) * 256 + c4 * 4);
        }
        __syncthreads();
#pragma unroll
        for (int kk = 0; kk < 32; ++kk) {
            float4 a0 = *(const float4*)&s_a[kk * 64 + ni * 4];
            float4 a1 = *(const float4*)&s_a[kk * 64 + ni * 4 + 32];
            float4 w0 = *(const float4*)&s_w[kk * 256 + di * 4];
            float4 w1 = *(const float4*)&s_w[kk * 256 + di * 4 + 128];
            float ar8[8] = {a0.x, a0.y, a0.z, a0.w, a1.x, a1.y, a1.z, a1.w};
            float wc8[8] = {w0.x, w0.y, w0.z, w0.w, w1.x, w1.y, w1.z, w1.w};
#pragma unroll
            for (int r = 0; r < 8; ++r)
#pragma unroll
                for (int cc = 0; cc < 8; ++cc)
                    acc[r][cc] = fmaf(ar8[r], wc8[cc], acc[r][cc]);
        }
    }

    float4 bb0 = *(const float4*)(bias + di * 4);
    float4 bb1 = *(const float4*)(bias + di * 4 + 128);
#pragma unroll
    for (int r = 0; r < 8; ++r) {
        int node = nb + ((r < 4) ? (ni * 4 + r) : (32 + ni * 4 + (r - 4)));
        if (node < N) {
            float4 o0 = {acc[r][0] + bb0.x, acc[r][1] + bb0.y,
                         acc[r][2] + bb0.z, acc[r][3] + bb0.w};
            float4 o1 = {acc[r][4] + bb1.x, acc[r][5] + bb1.y,
                         acc[r][6] + bb1.z, acc[r][7] + bb1.w};
            *(float4*)(C + (size_t)node * 256 + di * 4) = o0;
            *(float4*)(C + (size_t)node * 256 + di * 4 + 128) = o1;
        }
    }
}

// ---------------------------------------------------------------------------
// y = relu(LN(h1)*g + b) ; wave per node
// ---------------------------------------------------------------------------
__global__ __launch_bounds__(THREADS) void ln_relu_kernel(
    const float* __restrict__ h1, const float* __restrict__ g,
    const float* __restrict__ b, float* __restrict__ y, int N)
{
    const int wave = threadIdx.x >> 6;
    const int lane = threadIdx.x & 63;
    const int node = blockIdx.x * 4 + wave;
    if (node >= N) return;

    float4 v = *(const float4*)(h1 + (size_t)node * 256 + lane * 4);
    float s = v.x + v.y + v.z + v.w;
#pragma unroll
    for (int o = 32; o > 0; o >>= 1) s += __shfl_xor(s, o);
    float mu = s * (1.0f / 256.0f);
    float4 d = {v.x - mu, v.y - mu, v.z - mu, v.w - mu};
    float q = d.x * d.x + d.y * d.y + d.z * d.z + d.w * d.w;
#pragma unroll
    for (int o = 32; o > 0; o >>= 1) q += __shfl_xor(q, o);
    float var = q * (1.0f / 256.0f);
    float sc = 1.0f / sqrtf(var + 1e-5f);

    float4 gg = *(const float4*)(g + lane * 4);
    float4 bb = *(const float4*)(b + lane * 4);
    float4 o;
    o.x = reluf(d.x * sc * gg.x + bb.x);
    o.y = reluf(d.y * sc * gg.y + bb.y);
    o.z = reluf(d.z * sc * gg.z + bb.z);
    o.w = reluf(d.w * sc * gg.w + bb.w);
    *(float4*)(y + (size_t)node * 256 + lane * 4) = o;
}

extern "C" void kernel_launch(void* const* d_in, const int* in_sizes, int n_in,
                              void* d_out, int out_size, void* d_ws, size_t ws_size,
                              hipStream_t stream) {
    const float* x   = (const float*)d_in[0];
    const int*   ei  = (const int*)d_in[1];
    const float* ea  = (const float*)d_in[2];
    const float* ew1 = (const float*)d_in[3];
    const float* eb1 = (const float*)d_in[4];
    const float* ew2 = (const float*)d_in[5];
    const float* eb2 = (const float*)d_in[6];
    const float* lew = (const float*)d_in[7];
    const float* leb = (const float*)d_in[8];
    const float* w1  = (const float*)d_in[9];
    const float* b1  = (const float*)d_in[10];
    const float* lng = (const float*)d_in[11];
    const float* lnb = (const float*)d_in[12];
    const float* w2  = (const float*)d_in[13];
    const float* b2  = (const float*)d_in[14];
    float* out = (float*)d_out;

    const int N = in_sizes[0] / 256;
    const int E = in_sizes[1] / 2;

    float* aggr = (float*)d_ws;                    // N*256 f32
    float* h1   = aggr + (size_t)N * 256;          // N*256 f32
    // perm/counts live inside the (not-yet-needed) h1 region; gemm1 writes h1
    // only after edge_kernel has finished reading perm (same stream).
    int* perm   = (int*)h1;                        // E ints
    int* counts = perm + E;                        // N ints

    hipMemsetAsync(aggr, 0, (size_t)N * 256 * sizeof(float), stream);
    hipMemsetAsync(counts, 0, (size_t)N * sizeof(int), stream);

    hist_kernel<<<(E + 255) / 256, 256, 0, stream>>>(ei, counts, E);
    scan_kernel<<<1, 1024, 0, stream>>>(counts, N);
    scatter_kernel<<<(E + 255) / 256, 256, 0, stream>>>(ei, counts, perm, E);

    edge_kernel<<<E / ET, THREADS, 0, stream>>>(x, ei, ea, ew1, eb1, ew2, eb2,
                                                lew, leb, perm, aggr, E);

    const int gb = (N + 63) / 64;
    gemm_kernel<<<gb, THREADS, 0, stream>>>(x, aggr, w1, b1, h1, N);
    ln_relu_kernel<<<(N + 3) / 4, THREADS, 0, stream>>>(h1, lng, lnb, aggr, N);
    gemm_kernel<<<gb, THREADS, 0, stream>>>(aggr, nullptr, w2, b2, out, N);
}

// Round 3
// 1222.795 us; speedup vs baseline: 9.5368x; 4.1726x over previous
//
#include <hip/hip_runtime.h>
#include <cstdint>
#include <cstddef>

#define THREADS 256
#define ET 64

typedef __attribute__((ext_vector_type(8))) short short8;
typedef __attribute__((ext_vector_type(4))) float f32x4;

__device__ __forceinline__ float reluf(float v) { return fmaxf(v, 0.0f); }

__device__ __forceinline__ unsigned short f2bf(float f) {
    union { float f; unsigned u; } v; v.f = f;
    unsigned r = v.u + 0x7fff + ((v.u >> 16) & 1);   // RNE
    return (unsigned short)(r >> 16);
}

// ---------------------------------------------------------------------------
// Prep: W23T[n][k] = sum_j ew2[k][j]*lew[j][n]  (bf16), c2[n] = eb2 @ lew
// 256 blocks (one per n), 128 threads (one per k).
// ---------------------------------------------------------------------------
__global__ __launch_bounds__(128) void prep_kernel(
    const float* __restrict__ ew2, const float* __restrict__ eb2,
    const float* __restrict__ lew, unsigned short* __restrict__ w23t,
    float* __restrict__ c2)
{
    __shared__ float s_part[128];
    const int n = blockIdx.x;     // 0..255
    const int k = threadIdx.x;    // 0..127
    float acc = 0.0f;
#pragma unroll 4
    for (int j = 0; j < 128; ++j)
        acc = fmaf(ew2[k * 128 + j], lew[j * 256 + n], acc);
    w23t[n * 128 + k] = f2bf(acc);
    s_part[k] = eb2[k] * lew[k * 256 + n];
    __syncthreads();
    if (k == 0) {
        float s = 0.0f;
        for (int j = 0; j < 128; ++j) s += s_part[j];
        c2[n] = s;
    }
}

// ---------------------------------------------------------------------------
// Counting sort of edges by dst: hist -> exclusive scan -> scatter(perm)
// ---------------------------------------------------------------------------
__global__ __launch_bounds__(256) void hist_kernel(
    const int* __restrict__ ei, int* __restrict__ counts, int E)
{
    int e = blockIdx.x * 256 + threadIdx.x;
    if (e < E) atomicAdd(&counts[ei[(long long)E + e]], 1);
}

__global__ __launch_bounds__(1024) void scan_kernel(int* __restrict__ counts, int N)
{
    __shared__ int wsum[16];
    __shared__ int carry;
    const int tid = threadIdx.x;
    const int lane = tid & 63, wid = tid >> 6;
    if (tid == 0) carry = 0;
    __syncthreads();
    for (int chunk = 0; chunk < N; chunk += 1024) {
        int idx = chunk + tid;
        int v = (idx < N) ? counts[idx] : 0;
        int incl = v;
#pragma unroll
        for (int off = 1; off < 64; off <<= 1) {
            int t = __shfl_up(incl, off);
            if (lane >= off) incl += t;
        }
        if (lane == 63) wsum[wid] = incl;
        __syncthreads();
        int wpre = 0, tot = 0;
#pragma unroll
        for (int w = 0; w < 16; ++w) {
            int s = wsum[w];
            tot += s;
            if (w < wid) wpre += s;
        }
        int b = carry;
        if (idx < N) counts[idx] = b + wpre + incl - v;
        __syncthreads();
        if (tid == 0) carry = b + tot;
        __syncthreads();
    }
}

__global__ __launch_bounds__(256) void scatter_kernel(
    const int* __restrict__ ei, int* __restrict__ cursor,
    int* __restrict__ perm, int E)
{
    int e = blockIdx.x * 256 + threadIdx.x;
    if (e < E) {
        int d = ei[(long long)E + e];
        int pos = atomicAdd(&cursor[d], 1);
        perm[pos] = e;
    }
}

// ---------------------------------------------------------------------------
// Edge pipeline (dst-sorted, MFMA). Block = 64 edges, 4 waves.
// phase1 (fp32 VALU): hid = relu(raw@ew1+eb1) -> bf16 -> swizzled LDS tile.
// MFMA: emb_pre[64x256] = hid[64x128] @ W23T^T, wave w owns rows 16w..16w+15.
// epilogue: msg = relu(pol*(acc+c2) + leb + x[src]); in-lane suffix sum over
// 4 consecutive edge rows + 3-step chain across 16-lane groups; leaders
// atomically add into aggr[dst].
// ---------------------------------------------------------------------------
__global__ __launch_bounds__(THREADS, 2) void edge_mfma_kernel(
    const float* __restrict__ x, const int* __restrict__ ei,
    const float* __restrict__ ea,
    const float* __restrict__ ew1, const float* __restrict__ eb1,
    const unsigned short* __restrict__ w23t, const float* __restrict__ c2,
    const float* __restrict__ leb, const int* __restrict__ perm,
    float* __restrict__ aggr, int E)
{
    __shared__ float s_attr[ET * 17];
    __shared__ uint4 s_hid4[64 * 16];   // 64 rows x 256B, granule ^= row&15
    __shared__ int   s_pe[ET];
    __shared__ int   s_src[ET];
    __shared__ int   s_dst[ET];
    __shared__ float s_pol[ET];

    const int tid = threadIdx.x;
    const long long eb0 = (long long)blockIdx.x * ET;

    if (tid < ET) {
        int e = perm[eb0 + tid];
        s_pe[tid]  = e;
        s_src[tid] = ei[e];
        s_dst[tid] = ei[(long long)E + e];
    }
    __syncthreads();
    for (int i = tid; i < ET * 17; i += THREADS) {
        int idx = i / 17;
        int k = i - idx * 17;
        s_attr[i] = ea[(size_t)s_pe[idx] * 17 + k];
    }
    __syncthreads();
    if (tid < ET) s_pol[tid] = fminf(fmaxf(s_attr[tid * 17], 0.0f), 1.0f) + 0.01f;

    const int el = tid & 63;
    const int c  = tid >> 6;

    // ---- phase 1: hid = relu(raw @ ew1 + eb1); thread does dims 32c..32c+31
    float acc1[32];
#pragma unroll
    for (int j4 = 0; j4 < 8; ++j4) {
        float4 b = *(const float4*)(eb1 + c * 32 + j4 * 4);
        acc1[j4*4+0] = b.x; acc1[j4*4+1] = b.y;
        acc1[j4*4+2] = b.z; acc1[j4*4+3] = b.w;
    }
#pragma unroll
    for (int k = 0; k < 16; ++k) {
        float rk = s_attr[el * 17 + 1 + k];
#pragma unroll
        for (int j4 = 0; j4 < 8; ++j4) {
            float4 wv = *(const float4*)(ew1 + k * 128 + c * 32 + j4 * 4);
            acc1[j4*4+0] = fmaf(rk, wv.x, acc1[j4*4+0]);
            acc1[j4*4+1] = fmaf(rk, wv.y, acc1[j4*4+1]);
            acc1[j4*4+2] = fmaf(rk, wv.z, acc1[j4*4+2]);
            acc1[j4*4+3] = fmaf(rk, wv.w, acc1[j4*4+3]);
        }
    }
    // relu -> bf16 pack -> swizzled LDS write (granule ^= row&15)
#pragma unroll
    for (int q = 0; q < 4; ++q) {
        unsigned u0 = (unsigned)f2bf(reluf(acc1[q*8+0])) |
                      ((unsigned)f2bf(reluf(acc1[q*8+1])) << 16);
        unsigned u1 = (unsigned)f2bf(reluf(acc1[q*8+2])) |
                      ((unsigned)f2bf(reluf(acc1[q*8+3])) << 16);
        unsigned u2 = (unsigned)f2bf(reluf(acc1[q*8+4])) |
                      ((unsigned)f2bf(reluf(acc1[q*8+5])) << 16);
        unsigned u3 = (unsigned)f2bf(reluf(acc1[q*8+6])) |
                      ((unsigned)f2bf(reluf(acc1[q*8+7])) << 16);
        uint4 pk = {u0, u1, u2, u3};
        s_hid4[el * 16 + ((4 * c + q) ^ (el & 15))] = pk;
    }
    __syncthreads();

    // ---- MFMA: wave w -> edge rows 16w..16w+15, all 256 output dims ----
    const int lane = el;
    const int w = c;
    short8 afr[4];
#pragma unroll
    for (int kt = 0; kt < 4; ++kt) {
        int row = 16 * w + (lane & 15);
        afr[kt] = *(const short8*)&s_hid4[row * 16 + ((4 * kt + (lane >> 4)) ^ (lane & 15))];
    }
    const short8* wb = (const short8*)w23t;   // row n = 16 short8 chunks
    f32x4 acc[16];
#pragma unroll
    for (int nt = 0; nt < 16; ++nt) acc[nt] = (f32x4){0.f, 0.f, 0.f, 0.f};
#pragma unroll
    for (int kt = 0; kt < 4; ++kt) {
#pragma unroll
        for (int nt = 0; nt < 16; ++nt) {
            short8 b = wb[(nt * 16 + (lane & 15)) * 16 + 4 * kt + (lane >> 4)];
            acc[nt] = __builtin_amdgcn_mfma_f32_16x16x32_bf16(afr[kt], b, acc[nt], 0, 0, 0);
        }
    }

    // ---- epilogue: C-layout row m = 4*(lane>>4)+r, col n = 16*nt+(lane&15)
    const int g4 = lane >> 4, nl = lane & 15;
    int   d_[4], sr_[4];
    float p_[4];
#pragma unroll
    for (int r = 0; r < 4; ++r) {
        int erow = 16 * w + 4 * g4 + r;
        d_[r] = s_dst[erow]; sr_[r] = s_src[erow]; p_[r] = s_pol[erow];
    }
    float c2v[16], lbv[16];
#pragma unroll
    for (int nt = 0; nt < 16; ++nt) {
        c2v[nt] = c2[nt * 16 + nl];
        lbv[nt] = leb[nt * 16 + nl];
    }
#pragma unroll
    for (int r = 0; r < 4; ++r) {
        const float* xr = x + (size_t)sr_[r] * 256 + nl;
#pragma unroll
        for (int nt = 0; nt < 16; ++nt) {
            float m = fmaf(p_[r], acc[nt][r] + c2v[nt], lbv[nt]) + xr[nt * 16];
            acc[nt][r] = fmaxf(m, 0.0f);
        }
    }

    // ---- segmented reduce: in-lane suffix over r (4 consecutive edges) ----
#pragma unroll
    for (int r = 2; r >= 0; --r) {
        bool mm = (d_[r] == d_[r + 1]);
#pragma unroll
        for (int nt = 0; nt < 16; ++nt)
            if (mm) acc[nt][r] += acc[nt][r + 1];
    }
    // cross-group (16-lane quads) continuation: E = run-sum beyond my quad
    int d0n   = __shfl_down(d_[0], 16);
    int fulln = __shfl_down((int)(d_[0] == d_[3]), 16);
    bool cont = (g4 < 3) && (d_[3] == d0n);
    float Cn[16], Ev[16];
#pragma unroll
    for (int nt = 0; nt < 16; ++nt) {
        Cn[nt] = __shfl_down(acc[nt][0], 16);
        Ev[nt] = 0.0f;
    }
    for (int it = 0; it < 3; ++it) {
#pragma unroll
        for (int nt = 0; nt < 16; ++nt) {
            float En = __shfl_down(Ev[nt], 16);
            Ev[nt] = cont ? (Cn[nt] + (fulln ? En : 0.0f)) : 0.0f;
        }
    }
#pragma unroll
    for (int r = 0; r < 4; ++r) {
        bool tail = (d_[r] == d_[3]);
#pragma unroll
        for (int nt = 0; nt < 16; ++nt)
            if (tail) acc[nt][r] += Ev[nt];
    }
    // leaders write
    int dpl = __shfl_up(d_[3], 16);
    bool lead0 = (g4 == 0) || (d_[0] != dpl);
#pragma unroll
    for (int r = 0; r < 4; ++r) {
        bool ld = (r == 0) ? lead0 : (d_[r] != d_[r - 1]);
        if (ld) {
            float* ap = aggr + (size_t)d_[r] * 256 + nl;
#pragma unroll
            for (int nt = 0; nt < 16; ++nt)
                unsafeAtomicAdd(ap + nt * 16, acc[nt][r]);
        }
    }
}

// ---------------------------------------------------------------------------
// C[N,256] = (A1 (+A2)) @ W[256,256] + bias.  64-row tile, BK=32, 8x8 regs.
// ---------------------------------------------------------------------------
__global__ __launch_bounds__(THREADS) void gemm_kernel(
    const float* __restrict__ A1, const float* __restrict__ A2,
    const float* __restrict__ W, const float* __restrict__ bias,
    float* __restrict__ C, int N)
{
    __shared__ float s_a[32 * 64];    // [k][n]
    __shared__ float s_w[32 * 256];   // [k][d]

    const int tid = threadIdx.x;
    const int nb = blockIdx.x * 64;
    const int ni = tid >> 5;   // 0..7
    const int di = tid & 31;   // 0..31

    float acc[8][8];
#pragma unroll
    for (int r = 0; r < 8; ++r)
#pragma unroll
        for (int cc = 0; cc < 8; ++cc) acc[r][cc] = 0.0f;

    const int ln = tid >> 2;   // 0..63 (load row)
    const int kc = tid & 3;    // k-chunk
    const int arow = (nb + ln < N) ? (nb + ln) : (N - 1);
    const float* a1p = A1 + (size_t)arow * 256 + kc * 8;
    const float* a2p = A2 ? (A2 + (size_t)arow * 256 + kc * 8) : nullptr;

    for (int kb = 0; kb < 256; kb += 32) {
        float4 v0 = *(const float4*)(a1p + kb);
        float4 v1 = *(const float4*)(a1p + kb + 4);
        if (A2) {
            float4 u0 = *(const float4*)(a2p + kb);
            float4 u1 = *(const float4*)(a2p + kb + 4);
            v0.x += u0.x; v0.y += u0.y; v0.z += u0.z; v0.w += u0.w;
            v1.x += u1.x; v1.y += u1.y; v1.z += u1.z; v1.w += u1.w;
        }
        __syncthreads();  // previous tile's compute done
        s_a[(kc*8+0)*64 + ln] = v0.x; s_a[(kc*8+1)*64 + ln] = v0.y;
        s_a[(kc*8+2)*64 + ln] = v0.z; s_a[(kc*8+3)*64 + ln] = v0.w;
        s_a[(kc*8+4)*64 + ln] = v1.x; s_a[(kc*8+5)*64 + ln] = v1.y;
        s_a[(kc*8+6)*64 + ln] = v1.z; s_a[(kc*8+7)*64 + ln] = v1.w;
#pragma unroll
        for (int i = 0; i < 8; ++i) {
            int idx = tid + i * 256;          // float4 index 0..2047
            int row = idx >> 6, c4 = idx & 63;
            *(float4*)&s_w[row * 256 + c4 * 4] =
                *(const float4*)(W + (size_t)(kb + row) * 256 + c4 * 4);
        }
        __syncthreads();
#pragma unroll
        for (int kk = 0; kk < 32; ++kk) {
            float4 a0 = *(const float4*)&s_a[kk * 64 + ni * 4];
            float4 a1 = *(const float4*)&s_a[kk * 64 + ni * 4 + 32];
            float4 w0 = *(const float4*)&s_w[kk * 256 + di * 4];
            float4 w1 = *(const float4*)&s_w[kk * 256 + di * 4 + 128];
            float ar8[8] = {a0.x, a0.y, a0.z, a0.w, a1.x, a1.y, a1.z, a1.w};
            float wc8[8] = {w0.x, w0.y, w0.z, w0.w, w1.x, w1.y, w1.z, w1.w};
#pragma unroll
            for (int r = 0; r < 8; ++r)
#pragma unroll
                for (int cc = 0; cc < 8; ++cc)
                    acc[r][cc] = fmaf(ar8[r], wc8[cc], acc[r][cc]);
        }
    }

    float4 bb0 = *(const float4*)(bias + di * 4);
    float4 bb1 = *(const float4*)(bias + di * 4 + 128);
#pragma unroll
    for (int r = 0; r < 8; ++r) {
        int node = nb + ((r < 4) ? (ni * 4 + r) : (32 + ni * 4 + (r - 4)));
        if (node < N) {
            float4 o0 = {acc[r][0] + bb0.x, acc[r][1] + bb0.y,
                         acc[r][2] + bb0.z, acc[r][3] + bb0.w};
            float4 o1 = {acc[r][4] + bb1.x, acc[r][5] + bb1.y,
                         acc[r][6] + bb1.z, acc[r][7] + bb1.w};
            *(float4*)(C + (size_t)node * 256 + di * 4) = o0;
            *(float4*)(C + (size_t)node * 256 + di * 4 + 128) = o1;
        }
    }
}

// ---------------------------------------------------------------------------
// y = relu(LN(h1)*g + b) ; wave per node
// ---------------------------------------------------------------------------
__global__ __launch_bounds__(THREADS) void ln_relu_kernel(
    const float* __restrict__ h1, const float* __restrict__ g,
    const float* __restrict__ b, float* __restrict__ y, int N)
{
    const int wave = threadIdx.x >> 6;
    const int lane = threadIdx.x & 63;
    const int node = blockIdx.x * 4 + wave;
    if (node >= N) return;

    float4 v = *(const float4*)(h1 + (size_t)node * 256 + lane * 4);
    float s = v.x + v.y + v.z + v.w;
#pragma unroll
    for (int o = 32; o > 0; o >>= 1) s += __shfl_xor(s, o);
    float mu = s * (1.0f / 256.0f);
    float4 d = {v.x - mu, v.y - mu, v.z - mu, v.w - mu};
    float q = d.x * d.x + d.y * d.y + d.z * d.z + d.w * d.w;
#pragma unroll
    for (int o = 32; o > 0; o >>= 1) q += __shfl_xor(q, o);
    float var = q * (1.0f / 256.0f);
    float sc = 1.0f / sqrtf(var + 1e-5f);

    float4 gg = *(const float4*)(g + lane * 4);
    float4 bb = *(const float4*)(b + lane * 4);
    float4 o;
    o.x = reluf(d.x * sc * gg.x + bb.x);
    o.y = reluf(d.y * sc * gg.y + bb.y);
    o.z = reluf(d.z * sc * gg.z + bb.z);
    o.w = reluf(d.w * sc * gg.w + bb.w);
    *(float4*)(y + (size_t)node * 256 + lane * 4) = o;
}

extern "C" void kernel_launch(void* const* d_in, const int* in_sizes, int n_in,
                              void* d_out, int out_size, void* d_ws, size_t ws_size,
                              hipStream_t stream) {
    const float* x   = (const float*)d_in[0];
    const int*   ei  = (const int*)d_in[1];
    const float* ea  = (const float*)d_in[2];
    const float* ew1 = (const float*)d_in[3];
    const float* eb1 = (const float*)d_in[4];
    const float* ew2 = (const float*)d_in[5];
    const float* eb2 = (const float*)d_in[6];
    const float* lew = (const float*)d_in[7];
    const float* leb = (const float*)d_in[8];
    const float* w1  = (const float*)d_in[9];
    const float* b1  = (const float*)d_in[10];
    const float* lng = (const float*)d_in[11];
    const float* lnb = (const float*)d_in[12];
    const float* w2  = (const float*)d_in[13];
    const float* b2  = (const float*)d_in[14];
    float* out = (float*)d_out;

    const int N = in_sizes[0] / 256;
    const int E = in_sizes[1] / 2;

    float* aggr = (float*)d_ws;                    // N*256 f32
    float* h1   = aggr + (size_t)N * 256;          // N*256 f32
    // Scratch aliased into the h1 region: all of it is consumed before
    // gemm1 writes h1 (same stream, serial).
    int* perm   = (int*)h1;                        // E ints
    int* counts = perm + E;                        // N ints
    unsigned short* w23t = (unsigned short*)(counts + N);  // 256*128 bf16
    float* c2   = (float*)(w23t + 256 * 128);      // 256 f32

    hipMemsetAsync(aggr, 0, (size_t)N * 256 * sizeof(float), stream);
    hipMemsetAsync(counts, 0, (size_t)N * sizeof(int), stream);

    prep_kernel<<<256, 128, 0, stream>>>(ew2, eb2, lew, w23t, c2);
    hist_kernel<<<(E + 255) / 256, 256, 0, stream>>>(ei, counts, E);
    scan_kernel<<<1, 1024, 0, stream>>>(counts, N);
    scatter_kernel<<<(E + 255) / 256, 256, 0, stream>>>(ei, counts, perm, E);

    edge_mfma_kernel<<<E / ET, THREADS, 0, stream>>>(
        x, ei, ea, ew1, eb1, w23t, c2, leb, perm, aggr, E);

    const int gb = (N + 63) / 64;
    gemm_kernel<<<gb, THREADS, 0, stream>>>(x, aggr, w1, b1, h1, N);
    ln_relu_kernel<<<(N + 3) / 4, THREADS, 0, stream>>>(h1, lng, lnb, aggr, N);
    gemm_kernel<<<gb, THREADS, 0, stream>>>(aggr, nullptr, w2, b2, out, N);
}